// Round 10
// baseline (671.337 us; speedup 1.0000x reference)
//
#include <hip/hip_runtime.h>
#include <hip/hip_bf16.h>
#include <stdint.h>

#define BATCH 512
#define PIX   196
#define EDIM  2048
#define DDIM  512
#define ADIM  512
#define MROWS (BATCH*PIX)   // 100352 = 392*256

#define BM 256
#define BN 128
#define BK 32
#define NT (EDIM/BK)        // 64

typedef __attribute__((ext_vector_type(8))) short bf16x8;
typedef __attribute__((ext_vector_type(8))) float f32x8;
typedef __attribute__((ext_vector_type(8))) __bf16 bf16v8;
typedef __attribute__((ext_vector_type(4))) float f32x4;

#define GLL16(g, lptr) __builtin_amdgcn_global_load_lds( \
    (const __attribute__((address_space(1))) void*)(g),  \
    (__attribute__((address_space(3))) void*)(lptr), 16, 0, 0)

static __device__ __forceinline__ unsigned short f2bf(float f) {
  union { float f; uint32_t u; } v; v.f = f;
  uint32_t u = v.u;
  return (unsigned short)((u + 0x7FFFu + ((u >> 16) & 1u)) >> 16);  // RNE
}

// fp32x8 -> bf16x8 via compiler-selected v_cvt_pk_bf16_f32 (RNE)
static __device__ __forceinline__ bf16x8 cvt8(float4 a, float4 b) {
  f32x8 v = {a.x, a.y, a.z, a.w, b.x, b.y, b.z, b.w};
  bf16v8 c = __builtin_convertvector(v, bf16v8);
  bf16x8 r;
  __builtin_memcpy(&r, &c, 16);
  return r;
}

// ---------------- K0a: W_enc [2048][512] f32 -> Bt [512][2048] bf16 ----------
__global__ void k_transpose_wenc(const float* __restrict__ W,
                                 unsigned short* __restrict__ Bt) {
  __shared__ float tile[32][33];
  const int kt = blockIdx.x;
  const int nt = blockIdx.y;
  const int tx = threadIdx.x, ty = threadIdx.y;   // 32 x 8
#pragma unroll
  for (int j = 0; j < 4; j++)
    tile[ty + 8*j][tx] = W[(size_t)(kt*32 + ty + 8*j)*ADIM + nt*32 + tx];
  __syncthreads();
#pragma unroll
  for (int j = 0; j < 4; j++)
    Bt[(size_t)(nt*32 + ty + 8*j)*EDIM + kt*32 + tx] = f2bf(tile[tx][ty + 8*j]);
}

// ---------------- K0b: att2 = hidden @ W_dec + b_dec ------------------------
__global__ void k_att2(const float* __restrict__ H, const float* __restrict__ Wd,
                       const float* __restrict__ bd, float* __restrict__ att2) {
  __shared__ float h[DDIM];
  const int b = blockIdx.x;
  const int t = threadIdx.x;            // 256
  h[t]       = H[(size_t)b*DDIM + t];
  h[t + 256] = H[(size_t)b*DDIM + t + 256];
  __syncthreads();
  float a0 = 0.f, a1 = 0.f;
#pragma unroll 8
  for (int k = 0; k < DDIM; k++) {
    const float hv = h[k];
    a0 += hv * Wd[(size_t)k*ADIM + t];
    a1 += hv * Wd[(size_t)k*ADIM + t + 256];
  }
  att2[(size_t)b*ADIM + t]       = a0 + bd[t];
  att2[(size_t)b*ADIM + t + 256] = a1 + bd[t + 256];
}

// ---------------- K1: fused att1-GEMM + tanh + scores(partial) --------------
// 256x128 block, BK=32, 256 threads (4 waves 2Mx2N, wave tile 128x64).
// 2 LDS buffers = 49 KB -> TWO blocks/CU (independent barrier groups overlap
// each other's stalls). A: depth-2 reg prefetch (~2 tiles = ~1000cy HBM cover)
// -> cvt_pk bf16 -> swizzled ds_write. B: depth-1 global_load_lds (L2-hot).
// One barrier per K-tile, 32 MFMA between barriers, counted vmcnt (10/8),
// <=2-way LDS conflicts everywhere ((row>>1)&3 chunk XOR).
__global__ __launch_bounds__(256, 2) void k_gemm_scores(
    const float* __restrict__ enc,          // [M][2048] f32
    const unsigned short* __restrict__ Bt,  // [512][2048] bf16
    const float* __restrict__ b_enc,        // [512]
    const float* __restrict__ att2,         // [B][512]
    const float* __restrict__ W_full,       // [512]
    float* __restrict__ scores)             // [M] (pre-zeroed, atomicAdd)
{
  __shared__ __align__(16) char ldsA[2*16384];   // [buf][256 rows][32 bf16]
  __shared__ __align__(16) char ldsB[2*8192];    // [buf][128 rows][32 bf16]
  __shared__ float sc[BM];

  const int t   = threadIdx.x;          // 0..255
  const int l   = t & 63;
  const int wid = t >> 6;               // 0..3
  const int wr  = wid >> 1;             // 0..1 (M)
  const int wc  = wid & 1;              // 0..1 (N)

  // XCD swizzle (nwg=1568=8*196), n-minor: 4 N-tiles of one M-tile run
  // consecutively on one XCD -> A-tile fetched once, L2-reused 4x.
  const int orig = blockIdx.x;
  const int tile = (orig & 7) * 196 + (orig >> 3);
  const int bm0 = (tile >> 2) * BM;
  const int bn0 = (tile & 3) * BN;

  sc[t] = 0.f;

  // ---- A staging: thread -> row t>>2, fp32-chunk-pair p = t&3 (32B) ----
  const int arow = t >> 2;
  const int ap   = t & 3;
  const float* srcA = enc + (size_t)(bm0 + arow) * EDIM + ap * 8;
  const int wAb = arow*64 + ((ap ^ ((t >> 3) & 3)) * 16);   // +j*4096

  // ---- B staging: GLL linear dest; source chunk pre-XOR'd ----
  const unsigned short* srcB = Bt + (size_t)(bn0 + (t >> 2)) * EDIM
                               + ((t & 3) ^ ((t >> 3) & 3)) * 8;  // +j*64*EDIM
  const int dB = wid * 1024;            // + bufi*8192 + j*4096 ; lane*16 implicit

  // ---- fragment read addresses (all loop-invariant + immediates) ----
  const int l15 = l & 15, hi = l >> 4;
  const int swl = (l15 >> 1) & 3;
  const int addrA = (wr*128 + l15)*64 + ((hi ^ swl) * 16);  // + (mi)*1024
  const int addrB = (wc*64  + l15)*64 + ((hi ^ swl) * 16);  // + ni*1024

  float4 ar[2][4][2];   // [slot][j][half]
  bf16x8 af[4], bfr[4];
  f32x4 acc[8][4] = {};

#define A_ISSUE(SLOT, KT) do {                                   \
    _Pragma("unroll")                                            \
    for (int j = 0; j < 4; j++) {                                \
      const float* _s = srcA + (size_t)(j)*64*EDIM + (KT)*BK;    \
      ar[SLOT][j][0] = *(const float4*)(_s);                     \
      ar[SLOT][j][1] = *(const float4*)(_s + 4);                 \
    }                                                            \
  } while (0)

#define B_GLL(BUFI, KT) do {                                     \
    _Pragma("unroll")                                            \
    for (int j = 0; j < 2; j++)                                  \
      GLL16(srcB + (size_t)(j)*64*EDIM + (KT)*BK,                \
            ldsB + (BUFI)*8192 + j*4096 + dB);                   \
  } while (0)

#define A_WRITE(BUFI, SLOT) do {                                 \
    _Pragma("unroll")                                            \
    for (int j = 0; j < 4; j++) {                                \
      bf16x8 w = cvt8(ar[SLOT][j][0], ar[SLOT][j][1]);           \
      *(bf16x8*)(ldsA + (BUFI)*16384 + wAb + j*4096) = w;        \
    }                                                            \
  } while (0)

#define DSREAD_B(BUFI) do {                                      \
    _Pragma("unroll")                                            \
    for (int ni = 0; ni < 4; ni++)                               \
      bfr[ni] = *(const bf16x8*)(ldsB + (BUFI)*8192 + ni*1024 + addrB); \
  } while (0)

#define DSREAD_A(BUFI, MOFF) do {                                \
    _Pragma("unroll")                                            \
    for (int mi = 0; mi < 4; mi++)                               \
      af[mi] = *(const bf16x8*)(ldsA + (BUFI)*16384 + (mi+(MOFF))*1024 + addrA); \
  } while (0)

#define MF16(MOFF) do {                                          \
    _Pragma("unroll")                                            \
    for (int mi = 0; mi < 4; mi++)                               \
      _Pragma("unroll")                                          \
      for (int ni = 0; ni < 4; ni++)                             \
        acc[mi+(MOFF)][ni] = __builtin_amdgcn_mfma_f32_16x16x32_bf16( \
            af[mi], bfr[ni], acc[mi+(MOFF)][ni], 0, 0, 0);       \
  } while (0)

#define LGKM0_SB()                                               \
    asm volatile("s_waitcnt lgkmcnt(0)" ::: "memory");           \
    __builtin_amdgcn_sched_barrier(0)

  // Steady tile T (T<=61): CUR=T&1. In flight at top: A(T+1) [8, slot NXT].
  // Issue B(T+1)[2, buf NXT] then A(T+2)[8, slot CUR].
  // vmcnt(10) -> A(T+1) drained (B+A(T+2) fly); write it.
  // vmcnt(8)  -> B(T+1) drained (A(T+2) flies); barrier.
#define TILE_STEADY(T, CUR, NXT) do {                            \
    B_GLL(NXT, (T)+1);                                           \
    A_ISSUE(CUR, (T)+2);                                         \
    DSREAD_B(CUR); DSREAD_A(CUR, 0);                             \
    LGKM0_SB();                                                  \
    __builtin_amdgcn_s_setprio(1); MF16(0); __builtin_amdgcn_s_setprio(0); \
    DSREAD_A(CUR, 4);                                            \
    LGKM0_SB();                                                  \
    __builtin_amdgcn_s_setprio(1); MF16(4); __builtin_amdgcn_s_setprio(0); \
    asm volatile("s_waitcnt vmcnt(10)" ::: "memory");            \
    A_WRITE(NXT, NXT);                                           \
    asm volatile("s_waitcnt vmcnt(8) lgkmcnt(0)" ::: "memory");  \
    __builtin_amdgcn_s_barrier();                                \
  } while (0)

  // ---- prologue: A(0)->slot0, B(0)->buf0, A(1)->slot1 ----
  A_ISSUE(0, 0);
  B_GLL(0, 0);
  A_ISSUE(1, 1);
  asm volatile("s_waitcnt vmcnt(10)" ::: "memory");   // A(0) done
  A_WRITE(0, 0);
  asm volatile("s_waitcnt vmcnt(8) lgkmcnt(0)" ::: "memory");  // B(0) done
  __builtin_amdgcn_s_barrier();

  // ---- tiles 0..61 steady ----
  for (int kb = 0; kb < 62; kb += 2) {
    TILE_STEADY(kb,     0, 1);
    TILE_STEADY(kb + 1, 1, 0);
  }
  // ---- tile 62 (CUR=0): stage B(63); A(63) already in slot1 ----
  {
    B_GLL(1, 63);
    DSREAD_B(0); DSREAD_A(0, 0);
    LGKM0_SB();
    __builtin_amdgcn_s_setprio(1); MF16(0); __builtin_amdgcn_s_setprio(0);
    DSREAD_A(0, 4);
    LGKM0_SB();
    __builtin_amdgcn_s_setprio(1); MF16(4); __builtin_amdgcn_s_setprio(0);
    asm volatile("s_waitcnt vmcnt(2)" ::: "memory");  // A(63) done
    A_WRITE(1, 1);
    asm volatile("s_waitcnt vmcnt(0) lgkmcnt(0)" ::: "memory");
    __builtin_amdgcn_s_barrier();
  }
  // ---- tile 63 (CUR=1), no staging/barrier ----
  {
    DSREAD_B(1); DSREAD_A(1, 0);
    LGKM0_SB();
    MF16(0);
    DSREAD_A(1, 4);
    LGKM0_SB();
    MF16(4);
  }

  // epilogue: scores partial = sum_cols tanh(acc + b_enc + att2) * W_full
  float be[4], wf[4];
  int colv[4];
#pragma unroll
  for (int ni = 0; ni < 4; ni++) {
    colv[ni] = bn0 + wc*64 + ni*16 + l15;
    be[ni] = b_enc[colv[ni]];
    wf[ni] = W_full[colv[ni]];
  }
#pragma unroll
  for (int mi = 0; mi < 8; mi++) {
#pragma unroll
    for (int e = 0; e < 4; e++) {
      const int row_l = wr*128 + mi*16 + hi*4 + e;
      const unsigned gr = (unsigned)(bm0 + row_l);
      const unsigned b  = gr / 196u;
      float s = 0.f;
#pragma unroll
      for (int ni = 0; ni < 4; ni++) {
        const float v = acc[mi][ni][e] + be[ni] + att2[(size_t)b*ADIM + colv[ni]];
        s += tanhf(v) * wf[ni];
      }
      s += __shfl_xor(s, 1); s += __shfl_xor(s, 2);
      s += __shfl_xor(s, 4); s += __shfl_xor(s, 8);
      if (l15 == 0) atomicAdd(&sc[row_l], s);
    }
  }
  __syncthreads();
  atomicAdd(&scores[bm0 + t], sc[t]);
}

// ---------------- K2: softmax over P per batch (in place) -------------------
__global__ void k_softmax(float* __restrict__ sa) {   // [512][196]
  __shared__ float red[256];
  const int b = blockIdx.x, t = threadIdx.x;
  const float v = (t < PIX) ? sa[(size_t)b*PIX + t] : -1e30f;
  red[t] = v; __syncthreads();
  for (int s2 = 128; s2 > 0; s2 >>= 1) {
    if (t < s2) red[t] = fmaxf(red[t], red[t + s2]);
    __syncthreads();
  }
  const float m = red[0]; __syncthreads();
  const float e = (t < PIX) ? __expf(v - m) : 0.f;
  red[t] = e; __syncthreads();
  for (int s2 = 128; s2 > 0; s2 >>= 1) {
    if (t < s2) red[t] += red[t + s2];
    __syncthreads();
  }
  const float inv = 1.f / red[0];
  if (t < PIX) sa[(size_t)b*PIX + t] = e * inv;
}

// ---------------- K3: context = sum_p alpha[p] * enc[b][p][:] ---------------
__global__ __launch_bounds__(512) void k_context(
    const float* __restrict__ enc, const float* __restrict__ alpha,
    float* __restrict__ ctx) {
  __shared__ float al[PIX];
  const int b = blockIdx.x, t = threadIdx.x;
  if (t < PIX) al[t] = alpha[(size_t)b*PIX + t];
  __syncthreads();
  const float4* e4 = (const float4*)(enc + (size_t)b * PIX * EDIM);
  float4 acc = {0.f, 0.f, 0.f, 0.f};
#pragma unroll 4
  for (int p = 0; p < PIX; p++) {
    const float4 v = e4[(size_t)p * (EDIM/4) + t];
    const float a = al[p];
    acc.x += v.x * a; acc.y += v.y * a; acc.z += v.z * a; acc.w += v.w * a;
  }
  ((float4*)(ctx + (size_t)b * EDIM))[t] = acc;
}

// ---------------------------------------------------------------------------
extern "C" void kernel_launch(void* const* d_in, const int* in_sizes, int n_in,
                              void* d_out, int out_size, void* d_ws, size_t ws_size,
                              hipStream_t stream) {
  (void)in_sizes; (void)n_in; (void)out_size; (void)ws_size;
  const float* enc   = (const float*)d_in[0];
  const float* hid   = (const float*)d_in[1];
  const float* Wenc  = (const float*)d_in[2];
  const float* benc  = (const float*)d_in[3];
  const float* Wdec  = (const float*)d_in[4];
  const float* bdec  = (const float*)d_in[5];
  const float* Wfull = (const float*)d_in[6];
  // d_in[7] = b_full: softmax-invariant, unused.

  unsigned short* Bt = (unsigned short*)d_ws;                       // 2 MB
  float* att2 = (float*)((char*)d_ws + (size_t)ADIM * EDIM * 2);    // 1 MB
  float* ctx   = (float*)d_out;
  float* alpha = (float*)d_out + (size_t)BATCH * EDIM;              // scores live here

  hipMemsetAsync(alpha, 0, (size_t)MROWS * sizeof(float), stream);
  k_transpose_wenc<<<dim3(64, 16), dim3(32, 8), 0, stream>>>(Wenc, Bt);
  k_att2<<<BATCH, 256, 0, stream>>>(hid, Wdec, bdec, att2);
  k_gemm_scores<<<1568, 256, 0, stream>>>(enc, Bt, benc, att2, Wfull, alpha);
  k_softmax<<<BATCH, 256, 0, stream>>>(alpha);
  k_context<<<BATCH, 512, 0, stream>>>(enc, alpha, ctx);
}

// Round 11
// 645.022 us; speedup vs baseline: 1.0408x; 1.0408x over previous
//
#include <hip/hip_runtime.h>
#include <hip/hip_bf16.h>
#include <stdint.h>

#define BATCH 512
#define PIX   196
#define EDIM  2048
#define DDIM  512
#define ADIM  512
#define MROWS (BATCH*PIX)   // 100352 = 784*128

#define BM 128
#define BN 128
#define BK 32
#define NT (EDIM/BK)        // 64

typedef __attribute__((ext_vector_type(8))) short bf16x8;
typedef __attribute__((ext_vector_type(8))) float f32x8;
typedef __attribute__((ext_vector_type(8))) __bf16 bf16v8;
typedef __attribute__((ext_vector_type(4))) float f32x4;

#define GLL16(g, lptr) __builtin_amdgcn_global_load_lds( \
    (const __attribute__((address_space(1))) void*)(g),  \
    (__attribute__((address_space(3))) void*)(lptr), 16, 0, 0)

static __device__ __forceinline__ unsigned short f2bf(float f) {
  union { float f; uint32_t u; } v; v.f = f;
  uint32_t u = v.u;
  return (unsigned short)((u + 0x7FFFu + ((u >> 16) & 1u)) >> 16);  // RNE
}

// fp32x8 -> bf16x8 via compiler-selected v_cvt_pk_bf16_f32 (RNE)
static __device__ __forceinline__ bf16x8 cvt8(float4 a, float4 b) {
  f32x8 v = {a.x, a.y, a.z, a.w, b.x, b.y, b.z, b.w};
  bf16v8 c = __builtin_convertvector(v, bf16v8);
  bf16x8 r;
  __builtin_memcpy(&r, &c, 16);
  return r;
}

// ---------------- K0a: W_enc [2048][512] f32 -> Bt [512][2048] bf16 ----------
__global__ void k_transpose_wenc(const float* __restrict__ W,
                                 unsigned short* __restrict__ Bt) {
  __shared__ float tile[32][33];
  const int kt = blockIdx.x;
  const int nt = blockIdx.y;
  const int tx = threadIdx.x, ty = threadIdx.y;   // 32 x 8
#pragma unroll
  for (int j = 0; j < 4; j++)
    tile[ty + 8*j][tx] = W[(size_t)(kt*32 + ty + 8*j)*ADIM + nt*32 + tx];
  __syncthreads();
#pragma unroll
  for (int j = 0; j < 4; j++)
    Bt[(size_t)(nt*32 + ty + 8*j)*EDIM + kt*32 + tx] = f2bf(tile[tx][ty + 8*j]);
}

// ---------------- K0b: att2 = hidden @ W_dec + b_dec ------------------------
__global__ void k_att2(const float* __restrict__ H, const float* __restrict__ Wd,
                       const float* __restrict__ bd, float* __restrict__ att2) {
  __shared__ float h[DDIM];
  const int b = blockIdx.x;
  const int t = threadIdx.x;            // 256
  h[t]       = H[(size_t)b*DDIM + t];
  h[t + 256] = H[(size_t)b*DDIM + t + 256];
  __syncthreads();
  float a0 = 0.f, a1 = 0.f;
#pragma unroll 8
  for (int k = 0; k < DDIM; k++) {
    const float hv = h[k];
    a0 += hv * Wd[(size_t)k*ADIM + t];
    a1 += hv * Wd[(size_t)k*ADIM + t + 256];
  }
  att2[(size_t)b*ADIM + t]       = a0 + bd[t];
  att2[(size_t)b*ADIM + t + 256] = a1 + bd[t + 256];
}

// ---------------- K1: fused att1-GEMM + tanh + scores(partial) --------------
// m97-clone geometry: 128x128 block, 4 waves (2x2, wave tile 64x64), BK=32,
// 16 MFMA + 8 ds_read_b128 per wave per K-tile. A: fp32->reg->cvt_pk->
// swizzled ds_write (2 bufs). B: GLL16, pre-swizzled source, 3 bufs so the
// counted-vmcnt ledger never drains to 0 mid-loop (B(T+2) flies across the
// barrier). LDS = 40960 B exactly -> 4 blocks/CU = 16 waves (TLP hides the
// chain; m97 proves this structure at 12+ waves/CU).
__global__ __launch_bounds__(256, 4) void k_gemm_scores(
    const float* __restrict__ enc,          // [M][2048] f32
    const unsigned short* __restrict__ Bt,  // [512][2048] bf16
    const float* __restrict__ b_enc,        // [512]
    const float* __restrict__ att2,         // [B][512]
    const float* __restrict__ W_full,       // [512]
    float* __restrict__ scores)             // [M] (pre-zeroed, atomicAdd)
{
  __shared__ __align__(16) char ldsA[2*8192];   // [buf][128 rows][32 bf16]
  __shared__ __align__(16) char ldsB[3*8192];   // [buf][128 rows][32 bf16]

  const int t   = threadIdx.x;          // 0..255
  const int l   = t & 63;
  const int wid = t >> 6;               // 0..3
  const int wr  = wid >> 1;             // 0..1 (M)
  const int wc  = wid & 1;              // 0..1 (N)

  // XCD swizzle (nwg=3136=8*392), n-minor: 4 N-tiles of one M-tile run
  // consecutively on one XCD -> A-tile fetched once, L2-reused 4x.
  const int orig = blockIdx.x;
  const int tile = (orig & 7) * 392 + (orig >> 3);
  const int bm0 = (tile >> 2) * BM;
  const int bn0 = (tile & 3) * BN;

  // ---- A staging: thread -> row t>>1, 16 fp32 at col (t&1)*16 ----
  const int arow = t >> 1;
  const float* srcA = enc + (size_t)(bm0 + arow) * EDIM + (t & 1) * 16;
  const int g0  = (t & 1) * 2;
  const int wA0 = arow*64 + (((g0    ) ^ (arow & 3)) * 16);
  const int wA1 = arow*64 + (((g0 + 1) ^ (arow & 3)) * 16);

  // ---- B staging: GLL linear dest (byte idx*16, idx=j*256+t); LDS (row,c)
  //      holds global chunk c^(row&3) ----
  const unsigned short* srcB[2];
#pragma unroll
  for (int j = 0; j < 2; j++) {
    const int idx = j*256 + t;
    const int row = idx >> 2;
    srcB[j] = Bt + (size_t)(bn0 + row) * EDIM + ((idx & 3) ^ (row & 3)) * 8;
  }
  const int dB = wid * 1024;            // + buf*8192 + j*4096 ; lane*16 implicit

  // ---- fragment read addresses ----
  const int l15 = l & 15, hi = l >> 4;
  const int ck  = (hi ^ (l15 & 3)) * 16;
  const int baseA = wr*4096 + l15*64 + ck;   // + mi*1024 + bufA*8192
  const int baseB = wc*4096 + l15*64 + ck;   // + ni*1024 + bufB*8192

  float4 ar[4];
  bf16x8 af[4], bfr[4];
  f32x4 acc[4][4] = {};

#define A_ISSUE(KT) do {                                         \
    const float* _s = srcA + (size_t)(KT) * BK;                  \
    ar[0] = *(const float4*)(_s);                                \
    ar[1] = *(const float4*)(_s + 4);                            \
    ar[2] = *(const float4*)(_s + 8);                            \
    ar[3] = *(const float4*)(_s + 12);                           \
  } while (0)

#define B_GLL(BUF, KT) do {                                      \
    GLL16(srcB[0] + (size_t)(KT)*BK, ldsB + (BUF)*8192 + 0*4096 + dB); \
    GLL16(srcB[1] + (size_t)(KT)*BK, ldsB + (BUF)*8192 + 1*4096 + dB); \
  } while (0)

#define A_WRITE(BUF) do {                                        \
    bf16x8 w0 = cvt8(ar[0], ar[1]);                              \
    bf16x8 w1 = cvt8(ar[2], ar[3]);                              \
    *(bf16x8*)(ldsA + (BUF)*8192 + wA0) = w0;                    \
    *(bf16x8*)(ldsA + (BUF)*8192 + wA1) = w1;                    \
  } while (0)

#define COMPUTE(BA, BB) do {                                     \
    _Pragma("unroll")                                            \
    for (int ni = 0; ni < 4; ni++)                               \
      bfr[ni] = *(const bf16x8*)(ldsB + (BB)*8192 + ni*1024 + baseB); \
    _Pragma("unroll")                                            \
    for (int mi = 0; mi < 4; mi++)                               \
      af[mi] = *(const bf16x8*)(ldsA + (BA)*8192 + mi*1024 + baseA); \
    asm volatile("s_waitcnt lgkmcnt(0)" ::: "memory");           \
    __builtin_amdgcn_sched_barrier(0);                           \
    __builtin_amdgcn_s_setprio(1);                               \
    _Pragma("unroll")                                            \
    for (int mi = 0; mi < 4; mi++)                               \
      _Pragma("unroll")                                          \
      for (int ni = 0; ni < 4; ni++)                             \
        acc[mi][ni] = __builtin_amdgcn_mfma_f32_16x16x32_bf16(   \
            af[mi], bfr[ni], acc[mi][ni], 0, 0, 0);              \
    __builtin_amdgcn_s_setprio(0);                               \
  } while (0)

  // Steady tile T: entering, B(T+1) [2 loads] in flight.
  // Issue A(T+1)[4] then B(T+2)[2]; compute; vmcnt(2) -> A(T+1)+B(T+1)
  // drained, B(T+2) still flying; write A; barrier.
#define TILE(T, BA, BAN, BB, BBN) do {                           \
    A_ISSUE((T)+1);                                              \
    B_GLL(BBN, (T)+2);                                           \
    COMPUTE(BA, BB);                                             \
    asm volatile("s_waitcnt vmcnt(2)" ::: "memory");             \
    A_WRITE(BAN);                                                \
    asm volatile("s_waitcnt lgkmcnt(0)" ::: "memory");           \
    __builtin_amdgcn_s_barrier();                                \
  } while (0)

  // ---- prologue: A(0), B(0), B(1) ----
  A_ISSUE(0);
  B_GLL(0, 0);
  B_GLL(1, 1);
  asm volatile("s_waitcnt vmcnt(4)" ::: "memory");   // A(0) done
  A_WRITE(0);
  asm volatile("s_waitcnt vmcnt(2) lgkmcnt(0)" ::: "memory");  // B(0) done
  __builtin_amdgcn_s_barrier();

  // ---- tiles 0..59 (period 6 over (bufA, bufB)) ----
  for (int kb = 0; kb < 60; kb += 6) {
    TILE(kb+0, 0,1, 0,2);
    TILE(kb+1, 1,0, 1,0);
    TILE(kb+2, 0,1, 2,1);
    TILE(kb+3, 1,0, 0,2);
    TILE(kb+4, 0,1, 1,0);
    TILE(kb+5, 1,0, 2,1);
  }
  TILE(60, 0,1, 0,2);
  TILE(61, 1,0, 1,0);
  // ---- tile 62: issue A(63) only; full drain at end ----
  {
    A_ISSUE(63);
    COMPUTE(0, 2);
    asm volatile("s_waitcnt vmcnt(0)" ::: "memory");
    A_WRITE(1);
    asm volatile("s_waitcnt lgkmcnt(0)" ::: "memory");
    __builtin_amdgcn_s_barrier();
  }
  // ---- tile 63 ----
  COMPUTE(1, 0);

  // epilogue: scores partial = sum_cols tanh(acc + b_enc + att2) * W_full
  float be[4], wf[4];
  int colv[4];
#pragma unroll
  for (int ni = 0; ni < 4; ni++) {
    colv[ni] = bn0 + wc*64 + ni*16 + l15;
    be[ni] = b_enc[colv[ni]];
    wf[ni] = W_full[colv[ni]];
  }
#pragma unroll
  for (int mi = 0; mi < 4; mi++) {
#pragma unroll
    for (int e = 0; e < 4; e++) {
      const int row_l = wr*64 + mi*16 + hi*4 + e;
      const unsigned gr = (unsigned)(bm0 + row_l);
      const unsigned b  = gr / 196u;
      float s = 0.f;
#pragma unroll
      for (int ni = 0; ni < 4; ni++) {
        const float v = acc[mi][ni][e] + be[ni] + att2[(size_t)b*ADIM + colv[ni]];
        s += tanhf(v) * wf[ni];
      }
      s += __shfl_xor(s, 1); s += __shfl_xor(s, 2);
      s += __shfl_xor(s, 4); s += __shfl_xor(s, 8);
      if (l15 == 0) atomicAdd(&scores[gr], s);
    }
  }
}

// ---------------- K2: softmax over P per batch (in place) -------------------
__global__ void k_softmax(float* __restrict__ sa) {   // [512][196]
  __shared__ float red[256];
  const int b = blockIdx.x, t = threadIdx.x;
  const float v = (t < PIX) ? sa[(size_t)b*PIX + t] : -1e30f;
  red[t] = v; __syncthreads();
  for (int s2 = 128; s2 > 0; s2 >>= 1) {
    if (t < s2) red[t] = fmaxf(red[t], red[t + s2]);
    __syncthreads();
  }
  const float m = red[0]; __syncthreads();
  const float e = (t < PIX) ? __expf(v - m) : 0.f;
  red[t] = e; __syncthreads();
  for (int s2 = 128; s2 > 0; s2 >>= 1) {
    if (t < s2) red[t] += red[t + s2];
    __syncthreads();
  }
  const float inv = 1.f / red[0];
  if (t < PIX) sa[(size_t)b*PIX + t] = e * inv;
}

// ---------------- K3: context = sum_p alpha[p] * enc[b][p][:] ---------------
__global__ __launch_bounds__(512) void k_context(
    const float* __restrict__ enc, const float* __restrict__ alpha,
    float* __restrict__ ctx) {
  __shared__ float al[PIX];
  const int b = blockIdx.x, t = threadIdx.x;
  if (t < PIX) al[t] = alpha[(size_t)b*PIX + t];
  __syncthreads();
  const float4* e4 = (const float4*)(enc + (size_t)b * PIX * EDIM);
  float4 acc = {0.f, 0.f, 0.f, 0.f};
#pragma unroll 4
  for (int p = 0; p < PIX; p++) {
    const float4 v = e4[(size_t)p * (EDIM/4) + t];
    const float a = al[p];
    acc.x += v.x * a; acc.y += v.y * a; acc.z += v.z * a; acc.w += v.w * a;
  }
  ((float4*)(ctx + (size_t)b * EDIM))[t] = acc;
}

// ---------------------------------------------------------------------------
extern "C" void kernel_launch(void* const* d_in, const int* in_sizes, int n_in,
                              void* d_out, int out_size, void* d_ws, size_t ws_size,
                              hipStream_t stream) {
  (void)in_sizes; (void)n_in; (void)out_size; (void)ws_size;
  const float* enc   = (const float*)d_in[0];
  const float* hid   = (const float*)d_in[1];
  const float* Wenc  = (const float*)d_in[2];
  const float* benc  = (const float*)d_in[3];
  const float* Wdec  = (const float*)d_in[4];
  const float* bdec  = (const float*)d_in[5];
  const float* Wfull = (const float*)d_in[6];
  // d_in[7] = b_full: softmax-invariant, unused.

  unsigned short* Bt = (unsigned short*)d_ws;                       // 2 MB
  float* att2 = (float*)((char*)d_ws + (size_t)ADIM * EDIM * 2);    // 1 MB
  float* ctx   = (float*)d_out;
  float* alpha = (float*)d_out + (size_t)BATCH * EDIM;              // scores live here

  hipMemsetAsync(alpha, 0, (size_t)MROWS * sizeof(float), stream);
  k_transpose_wenc<<<dim3(64, 16), dim3(32, 8), 0, stream>>>(Wenc, Bt);
  k_att2<<<BATCH, 256, 0, stream>>>(hid, Wdec, bdec, att2);
  k_gemm_scores<<<3136, 256, 0, stream>>>(enc, Bt, benc, att2, Wfull, alpha);
  k_softmax<<<BATCH, 256, 0, stream>>>(alpha);
  k_context<<<BATCH, 512, 0, stream>>>(enc, alpha, ctx);
}